// Round 12
// baseline (459.988 us; speedup 1.0000x reference)
//
#include <hip/hip_runtime.h>
#include <hip/hip_bf16.h>

typedef __hip_bfloat16 bf16;

#define NPER 1024
#define CC   128
#define KK   64
#define NTOT 65536
#define ETOT 2097152

// ---------------- workspace layout (bytes), total 21,233,984 (~20.25 MiB) ----
#define M_OFF    0            // bf16 [NTOT*KK] = 8,388,608
#define R_OFF    8388608      // bf16 [NTOT*KK] = 8,388,608  (root, then S in place)
#define SORT_OFF 16777216     // u16  [ETOT]    = 4,194,304
#define RP_OFF   20971520     // int  [NTOT]    =   262,144  (destructive cursor)
#define FLAG_OFF 21233664     // int  [1]
#define ZB_OFF   21233728     // f32  [64]
#define WS_NEED  21233984ULL

// round-to-bf16 helper: matches the bf16-rounded expected values
__device__ __forceinline__ float g12_rb(float v) {
    return __bfloat162float(__float2bfloat16(v));
}

// ---- zero rowptr + fallback bias ----
__global__ void g12_init(int* __restrict__ rowptr, float* __restrict__ zbias) {
    int i = blockIdx.x * 512 + threadIdx.x;
    if (i < NTOT) rowptr[i] = 0;
    if (i < 64) zbias[i] = 0.f;
}

// ---- detect edge-index width: int32 (flag=1) vs int64-low-word (flag=2) ----
__global__ void g12_detect(const int* __restrict__ ei, int* __restrict__ flag) {
    __shared__ int sred[256];
    int t = threadIdx.x;
    int v = 0;
    for (int j = t; j < 65536; j += 256) v |= ei[2 * j + 1];
    sred[t] = v;
    __syncthreads();
    for (int off = 128; off; off >>= 1) {
        if (t < off) sred[t] |= sred[t + off];
        __syncthreads();
    }
    if (t == 0) *flag = (sred[0] != 0) ? 1 : 2;
}

__device__ __forceinline__ int g12_src(const int* ei, int e, int mode) {
    return (mode == 2 ? ei[2 * e] : ei[e]) & 65535;
}
__device__ __forceinline__ int g12_dst(const int* ei, int e, int mode) {
    return (mode == 2 ? ei[2 * ETOT + 2 * e] : ei[ETOT + e]) & 65535;
}

// ---- Stage 1: m = elu(x@Wm), root = x@Wr + b  (fp32 in, bf16 intermediates) ----
__global__ void g12_mroot(const float* __restrict__ x, const float* __restrict__ Wm,
                          const float* __restrict__ Wr, const float* __restrict__ bias,
                          bf16* __restrict__ m_out, bf16* __restrict__ root_out) {
    __shared__ bf16 sWm[CC * KK];
    __shared__ bf16 sWr[CC * KK];
    __shared__ bf16 sX[64 * CC];
    int t = threadIdx.x;
    int nb = blockIdx.x * 64;
    for (int i = t; i < CC * KK; i += 256) {
        sWm[i] = __float2bfloat16(Wm[i]);
        sWr[i] = __float2bfloat16(Wr[i]);
    }
    const float4* xg = (const float4*)(x + (size_t)nb * CC);
    for (int i = t; i < (64 * CC) / 4; i += 256) {
        float4 v = xg[i];
        sX[i * 4 + 0] = __float2bfloat16(v.x);
        sX[i * 4 + 1] = __float2bfloat16(v.y);
        sX[i * 4 + 2] = __float2bfloat16(v.z);
        sX[i * 4 + 3] = __float2bfloat16(v.w);
    }
    int k = t & 63, rg = t >> 6;
    float bv = bias[k];
    __syncthreads();
    float accm[16], accr[16];
#pragma unroll
    for (int r = 0; r < 16; ++r) { accm[r] = 0.f; accr[r] = 0.f; }
    for (int c = 0; c < CC; ++c) {
        float wm = __bfloat162float(sWm[c * KK + k]);
        float wr = __bfloat162float(sWr[c * KK + k]);
#pragma unroll
        for (int r = 0; r < 16; ++r) {
            float xv = __bfloat162float(sX[(rg + 4 * r) * CC + c]);
            accm[r] += xv * wm;
            accr[r] += xv * wr;
        }
    }
#pragma unroll
    for (int r = 0; r < 16; ++r) {
        int n = nb + rg + 4 * r;
        float mv = accm[r];
        mv = mv > 0.f ? mv : expm1f(mv);
        m_out[(size_t)n * KK + k] = __float2bfloat16(mv);
        root_out[(size_t)n * KK + k] = __float2bfloat16(accr[r] + bv);
    }
}

// ---- Stage 2a: histogram of dst into rowptr ----
__global__ void g12_hist(const int* __restrict__ ei, int* __restrict__ rowptr,
                         const int* __restrict__ flag) {
    int mode = *flag;
    int e = blockIdx.x * 256 + threadIdx.x;
    atomicAdd(&rowptr[g12_dst(ei, e, mode)], 1);
}

// ---- Stage 2b: in-place exclusive scan over rowptr (single block) ----
__global__ void g12_scan(int* __restrict__ rowptr) {
    __shared__ int ssum[1024];
    int t = threadIdx.x;
    int base = t * 64;
    int cnt[64];
    int s = 0;
    for (int j = 0; j < 64; ++j) { cnt[j] = rowptr[base + j]; s += cnt[j]; }
    ssum[t] = s;
    __syncthreads();
    for (int off = 1; off < 1024; off <<= 1) {
        int v = ssum[t];
        int a = (t >= off) ? ssum[t - off] : 0;
        __syncthreads();
        ssum[t] = v + a;
        __syncthreads();
    }
    int run = (t == 0) ? 0 : ssum[t - 1];
    for (int j = 0; j < 64; ++j) {
        rowptr[base + j] = run;
        run += cnt[j];
    }
}

// ---- Stage 2c: scatter src by dst; rowptr is destructive cursor (start->end) ----
__global__ void g12_scatter(const int* __restrict__ ei, int* __restrict__ rowptr,
                            unsigned short* __restrict__ sorted_src,
                            const int* __restrict__ flag) {
    int mode = *flag;
    int e = blockIdx.x * 256 + threadIdx.x;
    int s = g12_src(ei, e, mode);
    int d = g12_dst(ei, e, mode);
    int pos = atomicAdd(&rowptr[d], 1);
    if ((unsigned)pos < (unsigned)ETOT) sorted_src[pos] = (unsigned short)s;
}

// ---- Stage 3: gather-sum + tanh + softmax over K (one wave/node), S in place ----
__global__ void g12_gather(const int* __restrict__ rowptr,
                           const unsigned short* __restrict__ sorted_src,
                           const bf16* __restrict__ m_in, bf16* __restrict__ rootS) {
    int n = blockIdx.x * 4 + (threadIdx.x >> 6);
    int lane = threadIdx.x & 63;
    int start = (n == 0) ? 0 : rowptr[n - 1];
    int end = rowptr[n];
    if (start < 0) start = 0;
    if (start > ETOT) start = ETOT;
    if (end < start) end = start;
    if (end > ETOT) end = ETOT;
    float acc = __bfloat162float(rootS[(size_t)n * KK + lane]);
    int i = start;
    for (; i + 4 <= end; i += 4) {
        int s0 = sorted_src[i];
        int s1 = sorted_src[i + 1];
        int s2 = sorted_src[i + 2];
        int s3 = sorted_src[i + 3];
        float v0 = __bfloat162float(m_in[(size_t)s0 * KK + lane]);
        float v1 = __bfloat162float(m_in[(size_t)s1 * KK + lane]);
        float v2 = __bfloat162float(m_in[(size_t)s2 * KK + lane]);
        float v3 = __bfloat162float(m_in[(size_t)s3 * KK + lane]);
        acc += v0; acc += v1; acc += v2; acc += v3;
    }
    for (; i < end; ++i) {
        acc += __bfloat162float(m_in[(size_t)sorted_src[i] * KK + lane]);
    }
    float sv = tanhf(acc);
    float mx = sv;
    for (int o = 32; o; o >>= 1) mx = fmaxf(mx, __shfl_xor(mx, o, 64));
    float ev = expf(sv - mx);
    float sm = ev;
    for (int o = 32; o; o >>= 1) sm += __shfl_xor(sm, o, 64);
    rootS[(size_t)n * KK + lane] = __float2bfloat16(ev / sm);
}

// ---- Stage 4: out[b*K+k, c] = sum_n S[b,n,k]*x[b,n,c]  -> FLOAT32 d_out ----
__global__ void g12_pool(const float* __restrict__ x, const bf16* __restrict__ S_in,
                         float* __restrict__ outp) {
    __shared__ float sXf[64 * 32];
    __shared__ float sSf[64 * 64];
    int t = threadIdx.x;
    int gb = blockIdx.x >> 2;
    int q = blockIdx.x & 3;
    int cq = q * 32;
    int k0 = (t & 15) * 4;
    int c0 = (t >> 4) * 2;
    float acc[4][2];
#pragma unroll
    for (int a = 0; a < 4; ++a) { acc[a][0] = 0.f; acc[a][1] = 0.f; }
    for (int tile = 0; tile < 16; ++tile) {
        int nb = gb * NPER + tile * 64;
        for (int i = t; i < 64 * 32; i += 256) {
            int row = i >> 5, col = i & 31;
            sXf[i] = x[(size_t)(nb + row) * CC + cq + col];
        }
        for (int i = t; i < 64 * 64; i += 256) {
            sSf[i] = __bfloat162float(S_in[(size_t)nb * KK + i]);
        }
        __syncthreads();
        for (int j = 0; j < 64; ++j) {
            float sv0 = sSf[j * 64 + k0 + 0];
            float sv1 = sSf[j * 64 + k0 + 1];
            float sv2 = sSf[j * 64 + k0 + 2];
            float sv3 = sSf[j * 64 + k0 + 3];
            float x0 = sXf[j * 32 + c0];
            float x1 = sXf[j * 32 + c0 + 1];
            acc[0][0] += sv0 * x0; acc[0][1] += sv0 * x1;
            acc[1][0] += sv1 * x0; acc[1][1] += sv1 * x1;
            acc[2][0] += sv2 * x0; acc[2][1] += sv2 * x1;
            acc[3][0] += sv3 * x0; acc[3][1] += sv3 * x1;
        }
        __syncthreads();
    }
#pragma unroll
    for (int a = 0; a < 4; ++a) {
        outp[(size_t)(gb * KK + k0 + a) * CC + cq + c0 + 0] = g12_rb(acc[a][0]);
        outp[(size_t)(gb * KK + k0 + a) * CC + cq + c0 + 1] = g12_rb(acc[a][1]);
    }
}

// ---- Stage 5: edge_index_out + batch_out as FLOAT32 (bf16-rounded values) ----
__global__ void g12_edgefill(float* __restrict__ outp) {
    int gid = blockIdx.x * 256 + threadIdx.x;
    if (gid >= 528384) return;
    float val;
    if (gid < 524288) {
        int r = gid >> 18;        // row 0/1 of edge_index_out
        int rem = gid & 262143;
        int b = rem >> 12;        // graph
        int p = rem & 4095;       // pair index within graph
        int v = (r == 0) ? (p >> 6) : (p & 63);
        val = (float)(v + b * 64);
    } else {
        val = (float)((gid - 524288) >> 6);   // batch_out
    }
    outp[524288 + gid] = g12_rb(val);
}

extern "C" void kernel_launch(void* const* d_in, const int* in_sizes, int n_in,
                              void* d_out, int out_size, void* d_ws, size_t ws_size,
                              hipStream_t stream) {
    // ---- runtime size-matched input binding (robust to permutation) ----
    const float* x = nullptr; const int* ei = nullptr;
    const float* Wm = nullptr; const float* Wr = nullptr; const float* bias = nullptr;
    for (int i = 0; i < n_in; ++i) {
        int s = in_sizes[i];
        if (s == 8388608 && !x)       x  = (const float*)d_in[i];
        else if (s == 4194304 && !ei) ei = (const int*)d_in[i];
        else if (s == 8192) { if (!Wm) Wm = (const float*)d_in[i]; else if (!Wr) Wr = (const float*)d_in[i]; }
        else if (s == 64 && !bias)    bias = (const float*)d_in[i];
    }
    if (!x)  x  = (const float*)d_in[0];
    if (!ei) ei = (const int*)d_in[1];
    if (!Wm && n_in > 3) Wm = (const float*)d_in[3];
    if (!Wr && n_in > 4) Wr = (const float*)d_in[4];

    float* outp = (float*)d_out;           // d_out is FLOAT32 (fp32 reference outputs)
    bool out_ok = (out_size >= 1052672);
    bool ws_ok  = (ws_size >= WS_NEED) && x && ei && Wm && Wr;

    if (out_ok) {
        g12_edgefill<<<2064, 256, 0, stream>>>(outp);
    }
    if (out_ok && ws_ok) {
        char* ws = (char*)d_ws;
        bf16*           m_buf  = (bf16*)(ws + M_OFF);
        bf16*           rootS  = (bf16*)(ws + R_OFF);
        unsigned short* sorted = (unsigned short*)(ws + SORT_OFF);
        int*            rowptr = (int*)(ws + RP_OFF);
        int*            flag   = (int*)(ws + FLAG_OFF);
        float*          zbias  = (float*)(ws + ZB_OFF);
        const float* bz = bias ? bias : zbias;

        g12_init<<<128, 512, 0, stream>>>(rowptr, zbias);
        g12_detect<<<1, 256, 0, stream>>>(ei, flag);
        g12_hist<<<ETOT / 256, 256, 0, stream>>>(ei, rowptr, flag);
        g12_scan<<<1, 1024, 0, stream>>>(rowptr);
        g12_scatter<<<ETOT / 256, 256, 0, stream>>>(ei, rowptr, sorted, flag);
        g12_mroot<<<NTOT / 64, 256, 0, stream>>>(x, Wm, Wr, bz, m_buf, rootS);
        g12_gather<<<NTOT / 4, 256, 0, stream>>>(rowptr, sorted, m_buf, rootS);
        g12_pool<<<256, 256, 0, stream>>>(x, rootS, outp);
    }
}

// Round 13
// 394.018 us; speedup vs baseline: 1.1674x; 1.1674x over previous
//
#include <hip/hip_runtime.h>
#include <hip/hip_bf16.h>

typedef __hip_bfloat16 bf16;

#define NPER 1024
#define CC   128
#define KK   64
#define NTOT 65536
#define ETOT 2097152

// ---------------- workspace layout (bytes), total 21,233,984 (~20.25 MiB) ----
#define M_OFF    0            // bf16 [NTOT*KK] = 8,388,608
#define R_OFF    8388608      // bf16 [NTOT*KK] = 8,388,608  (root, then S in place)
#define SORT_OFF 16777216     // u16  [ETOT]    = 4,194,304
#define RP_OFF   20971520     // int  [NTOT]    =   262,144  (destructive cursor)
#define FLAG_OFF 21233664     // int  [1]
#define ZB_OFF   21233728     // f32  [64]
#define WS_NEED  21233984ULL

// round-to-bf16 helper: matches the bf16-rounded expected values
__device__ __forceinline__ float h13_rb(float v) {
    return __bfloat162float(__float2bfloat16(v));
}
__device__ __forceinline__ float h13_bf(unsigned short h) {
    unsigned int w = ((unsigned int)h) << 16;
    float f;
    __builtin_memcpy(&f, &w, 4);
    return f;
}

// ---- zero rowptr + fallback bias + flag ----
__global__ void h13_init(int* __restrict__ rowptr, float* __restrict__ zbias,
                         int* __restrict__ flag) {
    int i = blockIdx.x * 512 + threadIdx.x;
    if (i < NTOT) rowptr[i] = 0;
    if (i < 64) zbias[i] = 0.f;
    if (i == 0) flag[0] = 0;
}

// ---- parallel detect: OR of odd int32 words of src row (256 blocks) ----
// flag!=0 -> edges are int32 (mode 1); flag==0 -> int64 low-word (mode 2)
__global__ void h13_detect(const int* __restrict__ ei, int* __restrict__ flag) {
    __shared__ int sred[256];
    int t = threadIdx.x;
    int j = blockIdx.x * 256 + t;        // j in [0, 65536)
    sred[t] = ei[2 * j + 1];
    __syncthreads();
    for (int off = 128; off; off >>= 1) {
        if (t < off) sred[t] |= sred[t + off];
        __syncthreads();
    }
    if (t == 0 && sred[0] != 0) atomicOr(flag, 1);
}

__device__ __forceinline__ int h13_src(const int* ei, int e, int mode) {
    return (mode == 2 ? ei[2 * e] : ei[e]) & 65535;
}
__device__ __forceinline__ int h13_dst(const int* ei, int e, int mode) {
    return (mode == 2 ? ei[2 * ETOT + 2 * e] : ei[ETOT + e]) & 65535;
}

// ---- Stage 1: m = elu(x@Wm), root = x@Wr + b  (fp32 in, bf16 intermediates) ----
__global__ void h13_mroot(const float* __restrict__ x, const float* __restrict__ Wm,
                          const float* __restrict__ Wr, const float* __restrict__ bias,
                          bf16* __restrict__ m_out, bf16* __restrict__ root_out) {
    __shared__ bf16 sWm[CC * KK];
    __shared__ bf16 sWr[CC * KK];
    __shared__ bf16 sX[64 * CC];
    int t = threadIdx.x;
    int nb = blockIdx.x * 64;
    for (int i = t; i < CC * KK; i += 256) {
        sWm[i] = __float2bfloat16(Wm[i]);
        sWr[i] = __float2bfloat16(Wr[i]);
    }
    const float4* xg = (const float4*)(x + (size_t)nb * CC);
    for (int i = t; i < (64 * CC) / 4; i += 256) {
        float4 v = xg[i];
        sX[i * 4 + 0] = __float2bfloat16(v.x);
        sX[i * 4 + 1] = __float2bfloat16(v.y);
        sX[i * 4 + 2] = __float2bfloat16(v.z);
        sX[i * 4 + 3] = __float2bfloat16(v.w);
    }
    int k = t & 63, rg = t >> 6;
    float bv = bias[k];
    __syncthreads();
    float accm[16], accr[16];
#pragma unroll
    for (int r = 0; r < 16; ++r) { accm[r] = 0.f; accr[r] = 0.f; }
    for (int c = 0; c < CC; ++c) {
        float wm = __bfloat162float(sWm[c * KK + k]);
        float wr = __bfloat162float(sWr[c * KK + k]);
#pragma unroll
        for (int r = 0; r < 16; ++r) {
            float xv = __bfloat162float(sX[(rg + 4 * r) * CC + c]);
            accm[r] += xv * wm;
            accr[r] += xv * wr;
        }
    }
#pragma unroll
    for (int r = 0; r < 16; ++r) {
        int n = nb + rg + 4 * r;
        float mv = accm[r];
        mv = mv > 0.f ? mv : expm1f(mv);
        m_out[(size_t)n * KK + k] = __float2bfloat16(mv);
        root_out[(size_t)n * KK + k] = __float2bfloat16(accr[r] + bv);
    }
}

// ---- Stage 2a: histogram of dst into rowptr ----
__global__ void h13_hist(const int* __restrict__ ei, int* __restrict__ rowptr,
                         const int* __restrict__ flag) {
    int mode = (*flag != 0) ? 1 : 2;
    int e = blockIdx.x * 256 + threadIdx.x;
    atomicAdd(&rowptr[h13_dst(ei, e, mode)], 1);
}

// ---- Stage 2b: in-place exclusive scan over rowptr (single block) ----
__global__ void h13_scan(int* __restrict__ rowptr) {
    __shared__ int ssum[1024];
    int t = threadIdx.x;
    int base = t * 64;
    int cnt[64];
    int s = 0;
    for (int j = 0; j < 64; ++j) { cnt[j] = rowptr[base + j]; s += cnt[j]; }
    ssum[t] = s;
    __syncthreads();
    for (int off = 1; off < 1024; off <<= 1) {
        int v = ssum[t];
        int a = (t >= off) ? ssum[t - off] : 0;
        __syncthreads();
        ssum[t] = v + a;
        __syncthreads();
    }
    int run = (t == 0) ? 0 : ssum[t - 1];
    for (int j = 0; j < 64; ++j) {
        rowptr[base + j] = run;
        run += cnt[j];
    }
}

// ---- Stage 2c: scatter src by dst; rowptr is destructive cursor (start->end) ----
__global__ void h13_scatter(const int* __restrict__ ei, int* __restrict__ rowptr,
                            unsigned short* __restrict__ sorted_src,
                            const int* __restrict__ flag) {
    int mode = (*flag != 0) ? 1 : 2;
    int e = blockIdx.x * 256 + threadIdx.x;
    int s = h13_src(ei, e, mode);
    int d = h13_dst(ei, e, mode);
    int pos = atomicAdd(&rowptr[d], 1);
    if ((unsigned)pos < (unsigned)ETOT) sorted_src[pos] = (unsigned short)s;
}

// ---- Stage 3: gather-sum + tanh + softmax over K (one wave/node), S in place ----
__global__ void h13_gather(const int* __restrict__ rowptr,
                           const unsigned short* __restrict__ sorted_src,
                           const bf16* __restrict__ m_in, bf16* __restrict__ rootS) {
    int n = blockIdx.x * 4 + (threadIdx.x >> 6);
    int lane = threadIdx.x & 63;
    int start = (n == 0) ? 0 : rowptr[n - 1];
    int end = rowptr[n];
    if (start < 0) start = 0;
    if (start > ETOT) start = ETOT;
    if (end < start) end = start;
    if (end > ETOT) end = ETOT;
    float acc = __bfloat162float(rootS[(size_t)n * KK + lane]);
    int i = start;
    for (; i + 4 <= end; i += 4) {
        int s0 = sorted_src[i];
        int s1 = sorted_src[i + 1];
        int s2 = sorted_src[i + 2];
        int s3 = sorted_src[i + 3];
        float v0 = __bfloat162float(m_in[(size_t)s0 * KK + lane]);
        float v1 = __bfloat162float(m_in[(size_t)s1 * KK + lane]);
        float v2 = __bfloat162float(m_in[(size_t)s2 * KK + lane]);
        float v3 = __bfloat162float(m_in[(size_t)s3 * KK + lane]);
        acc += v0; acc += v1; acc += v2; acc += v3;
    }
    for (; i < end; ++i) {
        acc += __bfloat162float(m_in[(size_t)sorted_src[i] * KK + lane]);
    }
    float sv = tanhf(acc);
    float mx = sv;
    for (int o = 32; o; o >>= 1) mx = fmaxf(mx, __shfl_xor(mx, o, 64));
    float ev = expf(sv - mx);
    float sm = ev;
    for (int o = 32; o; o >>= 1) sm += __shfl_xor(sm, o, 64);
    rootS[(size_t)n * KK + lane] = __float2bfloat16(ev / sm);
}

// ---- Stage 4: out[b*K+k, c] = sum_n S[b,n,k]*x[b,n,c] -> fp32 d_out ----
// 512 threads: two j-halves in parallel; float4/float2 LDS vector loads.
__global__ __launch_bounds__(512) void h13_pool(const float* __restrict__ x,
                                                const bf16* __restrict__ S_in,
                                                float* __restrict__ outp) {
    __shared__ float sXf[64 * 32];     // 8 KB
    __shared__ float sSf[64 * 64];     // 16 KB
    __shared__ float sRed[256 * 9];    // 9 KB (pad 8->9 vs bank conflicts)
    int tt = threadIdx.x;
    int half = tt >> 8;
    int t = tt & 255;
    int gb = blockIdx.x >> 2;
    int q = blockIdx.x & 3;
    int cq = q * 32;
    int k0 = (t & 15) * 4;
    int c0 = (t >> 4) * 2;
    float acc[4][2];
#pragma unroll
    for (int a = 0; a < 4; ++a) { acc[a][0] = 0.f; acc[a][1] = 0.f; }
    int jbeg = half * 32, jend = jbeg + 32;
    for (int tile = 0; tile < 16; ++tile) {
        int nb = gb * NPER + tile * 64;
        for (int i = tt; i < 64 * 32; i += 512) {
            int row = i >> 5, col = i & 31;
            sXf[i] = x[(size_t)(nb + row) * CC + cq + col];
        }
        const uint2* sg = (const uint2*)(S_in + (size_t)nb * KK);
        for (int i = tt; i < 1024; i += 512) {
            uint2 u = sg[i];
            int b = i * 4;
            sSf[b + 0] = h13_bf((unsigned short)(u.x & 0xffff));
            sSf[b + 1] = h13_bf((unsigned short)(u.x >> 16));
            sSf[b + 2] = h13_bf((unsigned short)(u.y & 0xffff));
            sSf[b + 3] = h13_bf((unsigned short)(u.y >> 16));
        }
        __syncthreads();
        for (int j = jbeg; j < jend; ++j) {
            float4 sv = *(const float4*)(sSf + j * 64 + k0);
            float2 xv = *(const float2*)(sXf + j * 32 + c0);
            acc[0][0] += sv.x * xv.x; acc[0][1] += sv.x * xv.y;
            acc[1][0] += sv.y * xv.x; acc[1][1] += sv.y * xv.y;
            acc[2][0] += sv.z * xv.x; acc[2][1] += sv.z * xv.y;
            acc[3][0] += sv.w * xv.x; acc[3][1] += sv.w * xv.y;
        }
        __syncthreads();
    }
    if (half == 1) {
        float* r = sRed + t * 9;
        r[0] = acc[0][0]; r[1] = acc[0][1];
        r[2] = acc[1][0]; r[3] = acc[1][1];
        r[4] = acc[2][0]; r[5] = acc[2][1];
        r[6] = acc[3][0]; r[7] = acc[3][1];
    }
    __syncthreads();
    if (half == 0) {
        const float* r = sRed + t * 9;
        acc[0][0] += r[0]; acc[0][1] += r[1];
        acc[1][0] += r[2]; acc[1][1] += r[3];
        acc[2][0] += r[4]; acc[2][1] += r[5];
        acc[3][0] += r[6]; acc[3][1] += r[7];
#pragma unroll
        for (int a = 0; a < 4; ++a) {
            outp[(size_t)(gb * KK + k0 + a) * CC + cq + c0 + 0] = h13_rb(acc[a][0]);
            outp[(size_t)(gb * KK + k0 + a) * CC + cq + c0 + 1] = h13_rb(acc[a][1]);
        }
    }
}

// ---- Stage 5: edge_index_out + batch_out as fp32 (bf16-rounded values) ----
__global__ void h13_edgefill(float* __restrict__ outp) {
    int gid = blockIdx.x * 256 + threadIdx.x;
    if (gid >= 528384) return;
    float val;
    if (gid < 524288) {
        int r = gid >> 18;        // row 0/1 of edge_index_out
        int rem = gid & 262143;
        int b = rem >> 12;        // graph
        int p = rem & 4095;       // pair index within graph
        int v = (r == 0) ? (p >> 6) : (p & 63);
        val = (float)(v + b * 64);
    } else {
        val = (float)((gid - 524288) >> 6);   // batch_out
    }
    outp[524288 + gid] = h13_rb(val);
}

extern "C" void kernel_launch(void* const* d_in, const int* in_sizes, int n_in,
                              void* d_out, int out_size, void* d_ws, size_t ws_size,
                              hipStream_t stream) {
    // ---- runtime size-matched input binding (robust to permutation) ----
    const float* x = nullptr; const int* ei = nullptr;
    const float* Wm = nullptr; const float* Wr = nullptr; const float* bias = nullptr;
    for (int i = 0; i < n_in; ++i) {
        int s = in_sizes[i];
        if (s == 8388608 && !x)       x  = (const float*)d_in[i];
        else if (s == 4194304 && !ei) ei = (const int*)d_in[i];
        else if (s == 8192) { if (!Wm) Wm = (const float*)d_in[i]; else if (!Wr) Wr = (const float*)d_in[i]; }
        else if (s == 64 && !bias)    bias = (const float*)d_in[i];
    }
    if (!x)  x  = (const float*)d_in[0];
    if (!ei) ei = (const int*)d_in[1];
    if (!Wm && n_in > 3) Wm = (const float*)d_in[3];
    if (!Wr && n_in > 4) Wr = (const float*)d_in[4];

    float* outp = (float*)d_out;           // d_out is FLOAT32
    bool out_ok = (out_size >= 1052672);
    bool ws_ok  = (ws_size >= WS_NEED) && x && ei && Wm && Wr;

    if (out_ok) {
        h13_edgefill<<<2064, 256, 0, stream>>>(outp);
    }
    if (out_ok && ws_ok) {
        char* ws = (char*)d_ws;
        bf16*           m_buf  = (bf16*)(ws + M_OFF);
        bf16*           rootS  = (bf16*)(ws + R_OFF);
        unsigned short* sorted = (unsigned short*)(ws + SORT_OFF);
        int*            rowptr = (int*)(ws + RP_OFF);
        int*            flag   = (int*)(ws + FLAG_OFF);
        float*          zbias  = (float*)(ws + ZB_OFF);
        const float* bz = bias ? bias : zbias;

        h13_init<<<128, 512, 0, stream>>>(rowptr, zbias, flag);
        h13_detect<<<256, 256, 0, stream>>>(ei, flag);
        h13_hist<<<ETOT / 256, 256, 0, stream>>>(ei, rowptr, flag);
        h13_scan<<<1, 1024, 0, stream>>>(rowptr);
        h13_scatter<<<ETOT / 256, 256, 0, stream>>>(ei, rowptr, sorted, flag);
        h13_mroot<<<NTOT / 64, 256, 0, stream>>>(x, Wm, Wr, bz, m_buf, rootS);
        h13_gather<<<NTOT / 4, 256, 0, stream>>>(rowptr, sorted, m_buf, rootS);
        h13_pool<<<256, 512, 0, stream>>>(x, rootS, outp);
    }
}

// Round 14
// 291.658 us; speedup vs baseline: 1.5772x; 1.3510x over previous
//
#include <hip/hip_runtime.h>
#include <hip/hip_bf16.h>

typedef __hip_bfloat16 bf16;

#define NPER 1024
#define CC   128
#define KK   64
#define NTOT 65536
#define ETOT 2097152
#define EPG  32768   // edges per graph

// ---------------- workspace layout (bytes), total 21,233,984 (~20.25 MiB) ----
#define M_OFF    0            // bf16 [NTOT*KK] = 8,388,608
#define R_OFF    8388608      // bf16 [NTOT*KK] = 8,388,608  (root, then S in place)
#define SORT_OFF 16777216     // u16  [ETOT]    = 4,194,304
#define RP_OFF   20971520     // int  [NTOT]    =   262,144  (end-pointers)
#define FLAG_OFF 21233664     // int  [1]
#define ZB_OFF   21233728     // f32  [64]
#define WS_NEED  21233984ULL

// round-to-bf16 helper: matches the bf16-rounded expected values
__device__ __forceinline__ float s14_rb(float v) {
    return __bfloat162float(__float2bfloat16(v));
}
__device__ __forceinline__ float s14_bf(unsigned short h) {
    unsigned int w = ((unsigned int)h) << 16;
    float f;
    __builtin_memcpy(&f, &w, 4);
    return f;
}

// ---- init: fallback bias + flag (rowptr now fully written by sortg) ----
__global__ void s14_init(float* __restrict__ zbias, int* __restrict__ flag) {
    int i = threadIdx.x;
    if (i < 64) zbias[i] = 0.f;
    if (i == 0) flag[0] = 0;
}

// ---- parallel detect: OR of odd int32 words of src row (256 blocks) ----
// flag!=0 -> edges are int32 (mode 1); flag==0 -> int64 low-word (mode 2)
__global__ void s14_detect(const int* __restrict__ ei, int* __restrict__ flag) {
    __shared__ int sred[256];
    int t = threadIdx.x;
    int j = blockIdx.x * 256 + t;        // j in [0, 65536)
    sred[t] = ei[2 * j + 1];
    __syncthreads();
    for (int off = 128; off; off >>= 1) {
        if (t < off) sred[t] |= sred[t + off];
        __syncthreads();
    }
    if (t == 0 && sred[0] != 0) atomicOr(flag, 1);
}

__device__ __forceinline__ int s14_src(const int* ei, int e, int mode) {
    return (mode == 2 ? ei[2 * e] : ei[e]) & 65535;
}
__device__ __forceinline__ int s14_dst(const int* ei, int e, int mode) {
    return (mode == 2 ? ei[2 * ETOT + 2 * e] : ei[ETOT + e]) & 65535;
}

// ---- per-graph LDS counting sort: hist -> scan -> scatter, one block/graph ----
// Writes sorted[g*EPG .. ) (contiguous, single-XCD L2 resident) and
// rowptr[n] = end position of node n's segment (gather uses rowptr[n-1]..rowptr[n]).
__global__ __launch_bounds__(1024) void s14_sortg(const int* __restrict__ ei,
                                                  unsigned short* __restrict__ sorted,
                                                  int* __restrict__ rowptr,
                                                  const int* __restrict__ flag) {
    __shared__ int hist[NPER];    // then reused as local cursor
    __shared__ int sscan[NPER];
    int mode = (*flag != 0) ? 1 : 2;
    int t = threadIdx.x;
    int g = blockIdx.x;
    int ebase = g * EPG;
    hist[t] = 0;
    __syncthreads();
    // pass 1: histogram of local dst
    for (int i = t; i < EPG; i += 1024) {
        int d = s14_dst(ei, ebase + i, mode) & (NPER - 1);
        atomicAdd(&hist[d], 1);
    }
    __syncthreads();
    // inclusive scan (Hillis-Steele) over 1024 counts
    int cnt = hist[t];
    sscan[t] = cnt;
    __syncthreads();
    for (int off = 1; off < 1024; off <<= 1) {
        int v = sscan[t];
        int a = (t >= off) ? sscan[t - off] : 0;
        __syncthreads();
        sscan[t] = v + a;
        __syncthreads();
    }
    int incl = sscan[t];
    int excl = incl - cnt;
    hist[t] = excl;                       // local cursor
    rowptr[g * NPER + t] = ebase + incl;  // global end pointer
    __syncthreads();
    // pass 2: scatter src by dst using LDS cursor
    for (int i = t; i < EPG; i += 1024) {
        int e = ebase + i;
        int s = s14_src(ei, e, mode);
        int d = s14_dst(ei, e, mode) & (NPER - 1);
        int pos = atomicAdd(&hist[d], 1);
        if ((unsigned)pos < (unsigned)EPG) sorted[ebase + pos] = (unsigned short)s;
    }
}

// ---- Stage 1: m = elu(x@Wm), root = x@Wr + b  (fp32 in, bf16 intermediates) ----
__global__ void s14_mroot(const float* __restrict__ x, const float* __restrict__ Wm,
                          const float* __restrict__ Wr, const float* __restrict__ bias,
                          bf16* __restrict__ m_out, bf16* __restrict__ root_out) {
    __shared__ bf16 sWm[CC * KK];
    __shared__ bf16 sWr[CC * KK];
    __shared__ bf16 sX[64 * CC];
    int t = threadIdx.x;
    int nb = blockIdx.x * 64;
    for (int i = t; i < CC * KK; i += 256) {
        sWm[i] = __float2bfloat16(Wm[i]);
        sWr[i] = __float2bfloat16(Wr[i]);
    }
    const float4* xg = (const float4*)(x + (size_t)nb * CC);
    for (int i = t; i < (64 * CC) / 4; i += 256) {
        float4 v = xg[i];
        sX[i * 4 + 0] = __float2bfloat16(v.x);
        sX[i * 4 + 1] = __float2bfloat16(v.y);
        sX[i * 4 + 2] = __float2bfloat16(v.z);
        sX[i * 4 + 3] = __float2bfloat16(v.w);
    }
    int k = t & 63, rg = t >> 6;
    float bv = bias[k];
    __syncthreads();
    float accm[16], accr[16];
#pragma unroll
    for (int r = 0; r < 16; ++r) { accm[r] = 0.f; accr[r] = 0.f; }
    for (int c = 0; c < CC; ++c) {
        float wm = __bfloat162float(sWm[c * KK + k]);
        float wr = __bfloat162float(sWr[c * KK + k]);
#pragma unroll
        for (int r = 0; r < 16; ++r) {
            float xv = __bfloat162float(sX[(rg + 4 * r) * CC + c]);
            accm[r] += xv * wm;
            accr[r] += xv * wr;
        }
    }
#pragma unroll
    for (int r = 0; r < 16; ++r) {
        int n = nb + rg + 4 * r;
        float mv = accm[r];
        mv = mv > 0.f ? mv : expm1f(mv);
        m_out[(size_t)n * KK + k] = __float2bfloat16(mv);
        root_out[(size_t)n * KK + k] = __float2bfloat16(accr[r] + bv);
    }
}

// ---- Stage 3: gather-sum + tanh + softmax over K (one wave/node), S in place ----
__global__ void s14_gather(const int* __restrict__ rowptr,
                           const unsigned short* __restrict__ sorted_src,
                           const bf16* __restrict__ m_in, bf16* __restrict__ rootS) {
    int n = blockIdx.x * 4 + (threadIdx.x >> 6);
    int lane = threadIdx.x & 63;
    int start = (n == 0) ? 0 : rowptr[n - 1];
    int end = rowptr[n];
    if (start < 0) start = 0;
    if (start > ETOT) start = ETOT;
    if (end < start) end = start;
    if (end > ETOT) end = ETOT;
    float acc = __bfloat162float(rootS[(size_t)n * KK + lane]);
    int i = start;
    for (; i + 4 <= end; i += 4) {
        int s0 = sorted_src[i];
        int s1 = sorted_src[i + 1];
        int s2 = sorted_src[i + 2];
        int s3 = sorted_src[i + 3];
        float v0 = __bfloat162float(m_in[(size_t)s0 * KK + lane]);
        float v1 = __bfloat162float(m_in[(size_t)s1 * KK + lane]);
        float v2 = __bfloat162float(m_in[(size_t)s2 * KK + lane]);
        float v3 = __bfloat162float(m_in[(size_t)s3 * KK + lane]);
        acc += v0; acc += v1; acc += v2; acc += v3;
    }
    for (; i < end; ++i) {
        acc += __bfloat162float(m_in[(size_t)sorted_src[i] * KK + lane]);
    }
    float sv = tanhf(acc);
    float mx = sv;
    for (int o = 32; o; o >>= 1) mx = fmaxf(mx, __shfl_xor(mx, o, 64));
    float ev = expf(sv - mx);
    float sm = ev;
    for (int o = 32; o; o >>= 1) sm += __shfl_xor(sm, o, 64);
    rootS[(size_t)n * KK + lane] = __float2bfloat16(ev / sm);
}

// ---- Stage 4: out[b*K+k, c] = sum_n S[b,n,k]*x[b,n,c] -> fp32 d_out ----
// 512 threads: two j-halves in parallel; float4/float2 LDS vector loads.
__global__ __launch_bounds__(512) void s14_pool(const float* __restrict__ x,
                                                const bf16* __restrict__ S_in,
                                                float* __restrict__ outp) {
    __shared__ float sXf[64 * 32];     // 8 KB
    __shared__ float sSf[64 * 64];     // 16 KB
    __shared__ float sRed[256 * 9];    // 9 KB (pad 8->9 vs bank conflicts)
    int tt = threadIdx.x;
    int half = tt >> 8;
    int t = tt & 255;
    int gb = blockIdx.x >> 2;
    int q = blockIdx.x & 3;
    int cq = q * 32;
    int k0 = (t & 15) * 4;
    int c0 = (t >> 4) * 2;
    float acc[4][2];
#pragma unroll
    for (int a = 0; a < 4; ++a) { acc[a][0] = 0.f; acc[a][1] = 0.f; }
    int jbeg = half * 32, jend = jbeg + 32;
    for (int tile = 0; tile < 16; ++tile) {
        int nb = gb * NPER + tile * 64;
        for (int i = tt; i < 64 * 32; i += 512) {
            int row = i >> 5, col = i & 31;
            sXf[i] = x[(size_t)(nb + row) * CC + cq + col];
        }
        const uint2* sg = (const uint2*)(S_in + (size_t)nb * KK);
        for (int i = tt; i < 1024; i += 512) {
            uint2 u = sg[i];
            int b = i * 4;
            sSf[b + 0] = s14_bf((unsigned short)(u.x & 0xffff));
            sSf[b + 1] = s14_bf((unsigned short)(u.x >> 16));
            sSf[b + 2] = s14_bf((unsigned short)(u.y & 0xffff));
            sSf[b + 3] = s14_bf((unsigned short)(u.y >> 16));
        }
        __syncthreads();
        for (int j = jbeg; j < jend; ++j) {
            float4 sv = *(const float4*)(sSf + j * 64 + k0);
            float2 xv = *(const float2*)(sXf + j * 32 + c0);
            acc[0][0] += sv.x * xv.x; acc[0][1] += sv.x * xv.y;
            acc[1][0] += sv.y * xv.x; acc[1][1] += sv.y * xv.y;
            acc[2][0] += sv.z * xv.x; acc[2][1] += sv.z * xv.y;
            acc[3][0] += sv.w * xv.x; acc[3][1] += sv.w * xv.y;
        }
        __syncthreads();
    }
    if (half == 1) {
        float* r = sRed + t * 9;
        r[0] = acc[0][0]; r[1] = acc[0][1];
        r[2] = acc[1][0]; r[3] = acc[1][1];
        r[4] = acc[2][0]; r[5] = acc[2][1];
        r[6] = acc[3][0]; r[7] = acc[3][1];
    }
    __syncthreads();
    if (half == 0) {
        const float* r = sRed + t * 9;
        acc[0][0] += r[0]; acc[0][1] += r[1];
        acc[1][0] += r[2]; acc[1][1] += r[3];
        acc[2][0] += r[4]; acc[2][1] += r[5];
        acc[3][0] += r[6]; acc[3][1] += r[7];
#pragma unroll
        for (int a = 0; a < 4; ++a) {
            outp[(size_t)(gb * KK + k0 + a) * CC + cq + c0 + 0] = s14_rb(acc[a][0]);
            outp[(size_t)(gb * KK + k0 + a) * CC + cq + c0 + 1] = s14_rb(acc[a][1]);
        }
    }
}

// ---- Stage 5: edge_index_out + batch_out as fp32 (bf16-rounded values) ----
__global__ void s14_edgefill(float* __restrict__ outp) {
    int gid = blockIdx.x * 256 + threadIdx.x;
    if (gid >= 528384) return;
    float val;
    if (gid < 524288) {
        int r = gid >> 18;        // row 0/1 of edge_index_out
        int rem = gid & 262143;
        int b = rem >> 12;        // graph
        int p = rem & 4095;       // pair index within graph
        int v = (r == 0) ? (p >> 6) : (p & 63);
        val = (float)(v + b * 64);
    } else {
        val = (float)((gid - 524288) >> 6);   // batch_out
    }
    outp[524288 + gid] = s14_rb(val);
}

extern "C" void kernel_launch(void* const* d_in, const int* in_sizes, int n_in,
                              void* d_out, int out_size, void* d_ws, size_t ws_size,
                              hipStream_t stream) {
    // ---- runtime size-matched input binding (robust to permutation) ----
    const float* x = nullptr; const int* ei = nullptr;
    const float* Wm = nullptr; const float* Wr = nullptr; const float* bias = nullptr;
    for (int i = 0; i < n_in; ++i) {
        int s = in_sizes[i];
        if (s == 8388608 && !x)       x  = (const float*)d_in[i];
        else if (s == 4194304 && !ei) ei = (const int*)d_in[i];
        else if (s == 8192) { if (!Wm) Wm = (const float*)d_in[i]; else if (!Wr) Wr = (const float*)d_in[i]; }
        else if (s == 64 && !bias)    bias = (const float*)d_in[i];
    }
    if (!x)  x  = (const float*)d_in[0];
    if (!ei) ei = (const int*)d_in[1];
    if (!Wm && n_in > 3) Wm = (const float*)d_in[3];
    if (!Wr && n_in > 4) Wr = (const float*)d_in[4];

    float* outp = (float*)d_out;           // d_out is FLOAT32
    bool out_ok = (out_size >= 1052672);
    bool ws_ok  = (ws_size >= WS_NEED) && x && ei && Wm && Wr;

    if (out_ok) {
        s14_edgefill<<<2064, 256, 0, stream>>>(outp);
    }
    if (out_ok && ws_ok) {
        char* ws = (char*)d_ws;
        bf16*           m_buf  = (bf16*)(ws + M_OFF);
        bf16*           rootS  = (bf16*)(ws + R_OFF);
        unsigned short* sorted = (unsigned short*)(ws + SORT_OFF);
        int*            rowptr = (int*)(ws + RP_OFF);
        int*            flag   = (int*)(ws + FLAG_OFF);
        float*          zbias  = (float*)(ws + ZB_OFF);
        const float* bz = bias ? bias : zbias;

        s14_init<<<1, 64, 0, stream>>>(zbias, flag);
        s14_detect<<<256, 256, 0, stream>>>(ei, flag);
        s14_sortg<<<64, 1024, 0, stream>>>(ei, sorted, rowptr, flag);
        s14_mroot<<<NTOT / 64, 256, 0, stream>>>(x, Wm, Wr, bz, m_buf, rootS);
        s14_gather<<<NTOT / 4, 256, 0, stream>>>(rowptr, sorted, m_buf, rootS);
        s14_pool<<<256, 512, 0, stream>>>(x, rootS, outp);
    }
}

// Round 15
// 291.424 us; speedup vs baseline: 1.5784x; 1.0008x over previous
//
#include <hip/hip_runtime.h>
#include <hip/hip_bf16.h>

typedef __hip_bfloat16 bf16;

#define NPER 1024
#define CC   128
#define KK   64
#define NTOT 65536
#define ETOT 2097152
#define EPG  32768   // edges per graph

// ---------------- workspace layout (bytes), total 21,233,984 (~20.25 MiB) ----
#define M_OFF    0            // bf16 [NTOT*KK] = 8,388,608
#define R_OFF    8388608      // bf16 [NTOT*KK] = 8,388,608  (root, then S in place)
#define SORT_OFF 16777216     // u16  [ETOT]    = 4,194,304
#define RP_OFF   20971520     // int  [NTOT]    =   262,144  (end-pointers)
#define FLAG_OFF 21233664     // int  [1]      (unused now, kept for layout stability)
#define ZB_OFF   21233728     // f32  [64]
#define WS_NEED  21233984ULL

// round-to-bf16 helper: matches the bf16-rounded expected values
__device__ __forceinline__ float t15_rb(float v) {
    return __bfloat162float(__float2bfloat16(v));
}
__device__ __forceinline__ float t15_bf(unsigned short h) {
    unsigned int w = ((unsigned int)h) << 16;
    float f;
    __builtin_memcpy(&f, &w, 4);
    return f;
}

__device__ __forceinline__ int t15_src(const int* ei, int e, int mode) {
    return (mode == 2 ? ei[2 * e] : ei[e]) & 65535;
}
__device__ __forceinline__ int t15_dst(const int* ei, int e, int mode) {
    return (mode == 2 ? ei[2 * ETOT + 2 * e] : ei[ETOT + e]) & 65535;
}

// ---- per-graph LDS counting sort (+ local edge-width detect + zbias init) ----
// one 1024-thread block per graph; writes sorted[g*EPG..) contiguous and
// rowptr[n] = end of node n's segment.
__global__ __launch_bounds__(1024) void t15_sortg(const int* __restrict__ ei,
                                                  unsigned short* __restrict__ sorted,
                                                  int* __restrict__ rowptr,
                                                  float* __restrict__ zbias) {
    __shared__ int hist[NPER];    // scratch: detect-OR, then histogram/cursor
    __shared__ int sscan[NPER];
    __shared__ int smode;
    int t = threadIdx.x;
    int g = blockIdx.x;
    int ebase = g * EPG;
    if (g == 0 && t < 64) zbias[t] = 0.f;
    // local detect: OR 1024 odd int32 words within this block's src range.
    // int64 layout -> all high words zero; int32 layout -> random node ids.
    hist[t] = ei[2 * (ebase + t) + 1];
    __syncthreads();
    for (int off = 512; off; off >>= 1) {
        if (t < off) hist[t] |= hist[t + off];
        __syncthreads();
    }
    if (t == 0) smode = (hist[0] != 0) ? 1 : 2;
    __syncthreads();
    int mode = smode;
    hist[t] = 0;
    __syncthreads();
    // pass 1: histogram of local dst
    for (int i = t; i < EPG; i += 1024) {
        int d = t15_dst(ei, ebase + i, mode) & (NPER - 1);
        atomicAdd(&hist[d], 1);
    }
    __syncthreads();
    // inclusive scan (Hillis-Steele) over 1024 counts
    int cnt = hist[t];
    sscan[t] = cnt;
    __syncthreads();
    for (int off = 1; off < 1024; off <<= 1) {
        int v = sscan[t];
        int a = (t >= off) ? sscan[t - off] : 0;
        __syncthreads();
        sscan[t] = v + a;
        __syncthreads();
    }
    int incl = sscan[t];
    int excl = incl - cnt;
    hist[t] = excl;                       // local cursor
    rowptr[g * NPER + t] = ebase + incl;  // global end pointer
    __syncthreads();
    // pass 2: scatter src by dst using LDS cursor
    for (int i = t; i < EPG; i += 1024) {
        int e = ebase + i;
        int s = t15_src(ei, e, mode);
        int d = t15_dst(ei, e, mode) & (NPER - 1);
        int pos = atomicAdd(&hist[d], 1);
        if ((unsigned)pos < (unsigned)EPG) sorted[ebase + pos] = (unsigned short)s;
    }
}

// ---- Stage 1: m = elu(x@Wm), root = x@Wr + b  (fp32 in, bf16 intermediates) ----
__global__ void t15_mroot(const float* __restrict__ x, const float* __restrict__ Wm,
                          const float* __restrict__ Wr, const float* __restrict__ bias,
                          bf16* __restrict__ m_out, bf16* __restrict__ root_out) {
    __shared__ bf16 sWm[CC * KK];
    __shared__ bf16 sWr[CC * KK];
    __shared__ bf16 sX[64 * CC];
    int t = threadIdx.x;
    int nb = blockIdx.x * 64;
    for (int i = t; i < CC * KK; i += 256) {
        sWm[i] = __float2bfloat16(Wm[i]);
        sWr[i] = __float2bfloat16(Wr[i]);
    }
    const float4* xg = (const float4*)(x + (size_t)nb * CC);
    for (int i = t; i < (64 * CC) / 4; i += 256) {
        float4 v = xg[i];
        sX[i * 4 + 0] = __float2bfloat16(v.x);
        sX[i * 4 + 1] = __float2bfloat16(v.y);
        sX[i * 4 + 2] = __float2bfloat16(v.z);
        sX[i * 4 + 3] = __float2bfloat16(v.w);
    }
    int k = t & 63, rg = t >> 6;
    float bv = bias[k];
    __syncthreads();
    float accm[16], accr[16];
#pragma unroll
    for (int r = 0; r < 16; ++r) { accm[r] = 0.f; accr[r] = 0.f; }
    for (int c = 0; c < CC; ++c) {
        float wm = __bfloat162float(sWm[c * KK + k]);
        float wr = __bfloat162float(sWr[c * KK + k]);
#pragma unroll
        for (int r = 0; r < 16; ++r) {
            float xv = __bfloat162float(sX[(rg + 4 * r) * CC + c]);
            accm[r] += xv * wm;
            accr[r] += xv * wr;
        }
    }
#pragma unroll
    for (int r = 0; r < 16; ++r) {
        int n = nb + rg + 4 * r;
        float mv = accm[r];
        mv = mv > 0.f ? mv : expm1f(mv);
        m_out[(size_t)n * KK + k] = __float2bfloat16(mv);
        root_out[(size_t)n * KK + k] = __float2bfloat16(accr[r] + bv);
    }
}

// ---- Stage 3: gather-sum + tanh + softmax over K (one wave/node) ----
// sorted_src[i] is wave-uniform -> scalarize via readfirstlane so the m-row
// address is SGPR-base + loop-invariant lane offset; indices fetched 8-at-a-
// time as one aligned uint4.
__global__ __launch_bounds__(256) void t15_gather(const int* __restrict__ rowptr,
                           const unsigned short* __restrict__ sorted_src,
                           const unsigned short* __restrict__ m_in,
                           bf16* __restrict__ rootS) {
    int n = blockIdx.x * 4 + (threadIdx.x >> 6);
    int lane = threadIdx.x & 63;
    int start = (n == 0) ? 0 : rowptr[n - 1];
    int end = rowptr[n];
    if (start < 0) start = 0;
    if (start > ETOT) start = ETOT;
    if (end < start) end = start;
    if (end > ETOT) end = ETOT;
    float acc = t15_bf(((const unsigned short*)rootS)[(size_t)n * KK + lane]);
    int i = start;
    int pe = start + ((8 - (start & 7)) & 7);
    if (pe > end) pe = end;
    for (; i < pe; ++i) {
        unsigned s = __builtin_amdgcn_readfirstlane((unsigned)sorted_src[i]);
        acc += t15_bf(m_in[(size_t)s * KK + lane]);
    }
    for (; i + 8 <= end; i += 8) {
        uint4 u = *(const uint4*)(sorted_src + i);   // 16B aligned (i%8==0)
        unsigned w0 = __builtin_amdgcn_readfirstlane(u.x);
        unsigned w1 = __builtin_amdgcn_readfirstlane(u.y);
        unsigned w2 = __builtin_amdgcn_readfirstlane(u.z);
        unsigned w3 = __builtin_amdgcn_readfirstlane(u.w);
        float v0 = t15_bf(m_in[(size_t)(w0 & 0xffffu) * KK + lane]);
        float v1 = t15_bf(m_in[(size_t)(w0 >> 16) * KK + lane]);
        float v2 = t15_bf(m_in[(size_t)(w1 & 0xffffu) * KK + lane]);
        float v3 = t15_bf(m_in[(size_t)(w1 >> 16) * KK + lane]);
        float v4 = t15_bf(m_in[(size_t)(w2 & 0xffffu) * KK + lane]);
        float v5 = t15_bf(m_in[(size_t)(w2 >> 16) * KK + lane]);
        float v6 = t15_bf(m_in[(size_t)(w3 & 0xffffu) * KK + lane]);
        float v7 = t15_bf(m_in[(size_t)(w3 >> 16) * KK + lane]);
        acc += ((v0 + v1) + (v2 + v3)) + ((v4 + v5) + (v6 + v7));
    }
    for (; i < end; ++i) {
        unsigned s = __builtin_amdgcn_readfirstlane((unsigned)sorted_src[i]);
        acc += t15_bf(m_in[(size_t)s * KK + lane]);
    }
    float sv = tanhf(acc);
    float mx = sv;
    for (int o = 32; o; o >>= 1) mx = fmaxf(mx, __shfl_xor(mx, o, 64));
    float ev = expf(sv - mx);
    float sm = ev;
    for (int o = 32; o; o >>= 1) sm += __shfl_xor(sm, o, 64);
    rootS[(size_t)n * KK + lane] = __float2bfloat16(ev / sm);
}

// ---- Stage 4: out[b*K+k, c] = sum_n S[b,n,k]*x[b,n,c] -> fp32 d_out ----
__global__ __launch_bounds__(512) void t15_pool(const float* __restrict__ x,
                                                const bf16* __restrict__ S_in,
                                                float* __restrict__ outp) {
    __shared__ float sXf[64 * 32];     // 8 KB
    __shared__ float sSf[64 * 64];     // 16 KB
    __shared__ float sRed[256 * 9];    // 9 KB
    int tt = threadIdx.x;
    int half = tt >> 8;
    int t = tt & 255;
    int gb = blockIdx.x >> 2;
    int q = blockIdx.x & 3;
    int cq = q * 32;
    int k0 = (t & 15) * 4;
    int c0 = (t >> 4) * 2;
    float acc[4][2];
#pragma unroll
    for (int a = 0; a < 4; ++a) { acc[a][0] = 0.f; acc[a][1] = 0.f; }
    int jbeg = half * 32, jend = jbeg + 32;
    for (int tile = 0; tile < 16; ++tile) {
        int nb = gb * NPER + tile * 64;
        for (int i = tt; i < 64 * 32; i += 512) {
            int row = i >> 5, col = i & 31;
            sXf[i] = x[(size_t)(nb + row) * CC + cq + col];
        }
        const uint2* sg = (const uint2*)(S_in + (size_t)nb * KK);
        for (int i = tt; i < 1024; i += 512) {
            uint2 u = sg[i];
            int b = i * 4;
            sSf[b + 0] = t15_bf((unsigned short)(u.x & 0xffff));
            sSf[b + 1] = t15_bf((unsigned short)(u.x >> 16));
            sSf[b + 2] = t15_bf((unsigned short)(u.y & 0xffff));
            sSf[b + 3] = t15_bf((unsigned short)(u.y >> 16));
        }
        __syncthreads();
        for (int j = jbeg; j < jend; ++j) {
            float4 sv = *(const float4*)(sSf + j * 64 + k0);
            float2 xv = *(const float2*)(sXf + j * 32 + c0);
            acc[0][0] += sv.x * xv.x; acc[0][1] += sv.x * xv.y;
            acc[1][0] += sv.y * xv.x; acc[1][1] += sv.y * xv.y;
            acc[2][0] += sv.z * xv.x; acc[2][1] += sv.z * xv.y;
            acc[3][0] += sv.w * xv.x; acc[3][1] += sv.w * xv.y;
        }
        __syncthreads();
    }
    if (half == 1) {
        float* r = sRed + t * 9;
        r[0] = acc[0][0]; r[1] = acc[0][1];
        r[2] = acc[1][0]; r[3] = acc[1][1];
        r[4] = acc[2][0]; r[5] = acc[2][1];
        r[6] = acc[3][0]; r[7] = acc[3][1];
    }
    __syncthreads();
    if (half == 0) {
        const float* r = sRed + t * 9;
        acc[0][0] += r[0]; acc[0][1] += r[1];
        acc[1][0] += r[2]; acc[1][1] += r[3];
        acc[2][0] += r[4]; acc[2][1] += r[5];
        acc[3][0] += r[6]; acc[3][1] += r[7];
#pragma unroll
        for (int a = 0; a < 4; ++a) {
            outp[(size_t)(gb * KK + k0 + a) * CC + cq + c0 + 0] = t15_rb(acc[a][0]);
            outp[(size_t)(gb * KK + k0 + a) * CC + cq + c0 + 1] = t15_rb(acc[a][1]);
        }
    }
}

// ---- Stage 5: edge_index_out + batch_out as fp32 (bf16-rounded values) ----
__global__ void t15_edgefill(float* __restrict__ outp) {
    int gid = blockIdx.x * 256 + threadIdx.x;
    if (gid >= 528384) return;
    float val;
    if (gid < 524288) {
        int r = gid >> 18;        // row 0/1 of edge_index_out
        int rem = gid & 262143;
        int b = rem >> 12;        // graph
        int p = rem & 4095;       // pair index within graph
        int v = (r == 0) ? (p >> 6) : (p & 63);
        val = (float)(v + b * 64);
    } else {
        val = (float)((gid - 524288) >> 6);   // batch_out
    }
    outp[524288 + gid] = t15_rb(val);
}

extern "C" void kernel_launch(void* const* d_in, const int* in_sizes, int n_in,
                              void* d_out, int out_size, void* d_ws, size_t ws_size,
                              hipStream_t stream) {
    // ---- runtime size-matched input binding (robust to permutation) ----
    const float* x = nullptr; const int* ei = nullptr;
    const float* Wm = nullptr; const float* Wr = nullptr; const float* bias = nullptr;
    for (int i = 0; i < n_in; ++i) {
        int s = in_sizes[i];
        if (s == 8388608 && !x)       x  = (const float*)d_in[i];
        else if (s == 4194304 && !ei) ei = (const int*)d_in[i];
        else if (s == 8192) { if (!Wm) Wm = (const float*)d_in[i]; else if (!Wr) Wr = (const float*)d_in[i]; }
        else if (s == 64 && !bias)    bias = (const float*)d_in[i];
    }
    if (!x)  x  = (const float*)d_in[0];
    if (!ei) ei = (const int*)d_in[1];
    if (!Wm && n_in > 3) Wm = (const float*)d_in[3];
    if (!Wr && n_in > 4) Wr = (const float*)d_in[4];

    float* outp = (float*)d_out;           // d_out is FLOAT32
    bool out_ok = (out_size >= 1052672);
    bool ws_ok  = (ws_size >= WS_NEED) && x && ei && Wm && Wr;

    if (out_ok) {
        t15_edgefill<<<2064, 256, 0, stream>>>(outp);
    }
    if (out_ok && ws_ok) {
        char* ws = (char*)d_ws;
        bf16*           m_buf  = (bf16*)(ws + M_OFF);
        bf16*           rootS  = (bf16*)(ws + R_OFF);
        unsigned short* sorted = (unsigned short*)(ws + SORT_OFF);
        int*            rowptr = (int*)(ws + RP_OFF);
        float*          zbias  = (float*)(ws + ZB_OFF);
        const float* bz = bias ? bias : zbias;

        t15_sortg<<<64, 1024, 0, stream>>>(ei, sorted, rowptr, zbias);
        t15_mroot<<<NTOT / 64, 256, 0, stream>>>(x, Wm, Wr, bz, m_buf, rootS);
        t15_gather<<<NTOT / 4, 256, 0, stream>>>(rowptr, sorted,
                                                 (const unsigned short*)m_buf, rootS);
        t15_pool<<<256, 512, 0, stream>>>(x, rootS, outp);
    }
}